// Round 2
// baseline (81.283 us; speedup 1.0000x reference)
//
#include <hip/hip_runtime.h>
#include <hip/hip_bf16.h>

#define TPB 256
#define GRIDBLK 1024

__device__ __forceinline__ void cubic_w(float t, float w[4]) {
    // A = -0.75 ; s = 1-t
    float s = 1.0f - t;
    float t2 = t * t;
    float s2 = s * s;
    w[0] = -0.75f * t * s2;                       // A*t*s^2
    w[1] = 1.25f * (t2 * t) - 2.25f * t2 + 1.0f;  // (A+2)t^3-(A+3)t^2+1
    w[2] = 1.25f * (s2 * s) - 2.25f * s2 + 1.0f;
    w[3] = -0.75f * s * t2;
}

__device__ __forceinline__ int reflect64(int v) {
    // valid for v in [-126, 126]; actual range here is [-2, 64]
    v = v < 0 ? -v : v;
    v = v > 63 ? 126 - v : v;
    // defensive clamp (matches jnp.clip in reference)
    v = v < 0 ? 0 : (v > 63 ? 63 : v);
    return v;
}

__global__ __launch_bounds__(TPB) void deformation_field_kernel(
        const float4* __restrict__ coord4,   // (y0,x0,y1,x1) = two coords per float4
        const float4* __restrict__ depl4,    // 2*64*64 floats = 2048 float4
        const float4* __restrict__ mask4,
        float4* __restrict__ out4,           // (a0,a1) fp32 for two coords per float4
        int n_pairs)
{
    // channel-interleaved masked image: img[y*64+x] = (c0, c1). 32 KB LDS.
    __shared__ float2 img[64 * 64];

    for (int i = threadIdx.x; i < 1024; i += TPB) {
        float4 d0 = depl4[i];          // channel 0, pixels 4i..4i+3
        float4 m0 = mask4[i];
        float4 d1 = depl4[1024 + i];   // channel 1
        float4 m1 = mask4[1024 + i];
        int o = i * 4;
        img[o + 0] = make_float2(d0.x * m0.x, d1.x * m1.x);
        img[o + 1] = make_float2(d0.y * m0.y, d1.y * m1.y);
        img[o + 2] = make_float2(d0.z * m0.z, d1.z * m1.z);
        img[o + 3] = make_float2(d0.w * m0.w, d1.w * m1.w);
    }
    __syncthreads();

    const int stride = gridDim.x * blockDim.x;
    for (int p = blockIdx.x * blockDim.x + threadIdx.x; p < n_pairs; p += stride) {
        float4 c = coord4[p];
        float cy[2] = {c.x, c.z};
        float cx[2] = {c.y, c.w};
        float res[4];
        #pragma unroll
        for (int q = 0; q < 2; ++q) {
            // crop = 1/64 = 0.015625 ; scale = 0.5*(64-1) = 31.5
            float gx = cx[q] - 0.015625f;
            float gy = cy[q] - 0.015625f;
            float ix = (gx + 1.0f) * 31.5f;
            float iy = (gy + 1.0f) * 31.5f;
            float fx0 = floorf(ix);
            float fy0 = floorf(iy);
            float tx = ix - fx0;
            float ty = iy - fy0;
            int jx = (int)fx0;
            int jy = (int)fy0;

            float wx[4], wy[4];
            cubic_w(tx, wx);
            cubic_w(ty, wy);

            int xs[4], ysr[4];
            #pragma unroll
            for (int k = 0; k < 4; ++k) {
                xs[k]  = reflect64(jx + k - 1);
                ysr[k] = reflect64(jy + k - 1);
            }

            float a0 = 0.0f, a1 = 0.0f;
            #pragma unroll
            for (int i = 0; i < 4; ++i) {
                int rb = ysr[i] << 6;
                float r0 = 0.0f, r1 = 0.0f;
                #pragma unroll
                for (int j = 0; j < 4; ++j) {
                    float2 v = img[rb + xs[j]];
                    r0 = fmaf(wx[j], v.x, r0);
                    r1 = fmaf(wx[j], v.y, r1);
                }
                a0 = fmaf(wy[i], r0, a0);
                a1 = fmaf(wy[i], r1, a1);
            }

            res[2 * q + 0] = a0;  // out[b][0]
            res[2 * q + 1] = a1;  // out[b][1]
        }
        out4[p] = make_float4(res[0], res[1], res[2], res[3]);
    }
}

extern "C" void kernel_launch(void* const* d_in, const int* in_sizes, int n_in,
                              void* d_out, int out_size, void* d_ws, size_t ws_size,
                              hipStream_t stream) {
    const float4* coord4 = (const float4*)d_in[0];  // (B,2) f32
    const float4* depl4  = (const float4*)d_in[1];  // (2,64,64) f32
    const float4* mask4  = (const float4*)d_in[2];  // (2,64,64) f32
    float4* out4 = (float4*)d_out;                  // (B,2) f32 -> B/2 float4

    int n_pairs = in_sizes[0] / 4;  // B/2
    int grid = GRIDBLK;
    int max_grid = (n_pairs + TPB - 1) / TPB;
    if (grid > max_grid) grid = max_grid;

    deformation_field_kernel<<<grid, TPB, 0, stream>>>(coord4, depl4, mask4, out4, n_pairs);
}